// Round 4
// baseline (566.594 us; speedup 1.0000x reference)
//
#include <hip/hip_runtime.h>
#include <math.h>

typedef _Float16 half_t;
typedef half_t half8 __attribute__((ext_vector_type(8)));
typedef float f32x4 __attribute__((ext_vector_type(4)));

#define PI_F 3.14159265358979323846f

// Fast tanh: (e^{2z}-1) * rcp(e^{2z}+1) via native v_exp_f32 / v_rcp_f32.
// Clamp keeps e^{2z} finite (avoids inf*0 = NaN); tanh saturates long before.
__device__ __forceinline__ float ftanh(float z) {
    z = fminf(fmaxf(z, -15.f), 15.f);
    const float t = __expf(2.f * z);          // v_exp_f32
    return (t - 1.f) * __builtin_amdgcn_rcpf(t + 1.f);
}

// J LDS layout: 192 rows (m = comp*16 + point) x 64 half cols (k = neuron).
// Row = 8 granules of 8 halves (16B); granule column rotated by
// s(m) = (m + m>>3) & 7 so the 16 rows of an A-fragment read map to
// distinct-ish bank groups (plain row-major would be a 16-way conflict).
__device__ __forceinline__ int swidx(int m, int col) {
    const int s = (m + (m >> 3)) & 7;
    return m * 64 + ((((col >> 3) + s) & 7) << 3) + (col & 7);
}

__global__ __launch_bounds__(512, 6) void pinn_main(
    const float* __restrict__ pts,
    const float* __restrict__ W1, const float* __restrict__ b1,
    const float* __restrict__ b2, const float* __restrict__ b3,
    const half_t* __restrict__ wsH,    // Wt2 @0, Wt3 @4096, Wo @8192 (half idx)
    float* __restrict__ partial)
{
    __shared__ half_t J[2][192 * 64];   // 2 units x 24 KB
    __shared__ float rbuf[8];

    const int tid  = threadIdx.x;
    const int unit = tid >> 8;          // 16-point unit (4 waves each)
    const int l    = tid & 63;
    const int w    = (tid >> 6) & 3;    // wave within unit = N-tile
    const int q    = l >> 4;
    const int i    = l & 15;
    const int j    = w * 16 + i;        // output-neuron column owned
    half_t* Jl = J[unit];

    const int pbase = blockIdx.x * 32 + unit * 16;

    // points p = q*4 + r live in this lane's registers
    float px[4], pt[4];
    #pragma unroll
    for (int r = 0; r < 4; ++r) {
        const float2 xy = *(const float2*)(pts + 2 * (pbase + q * 4 + r));
        px[r] = xy.x; pt[r] = xy.y;
    }

    // ---------------- layer 1 (2 -> 64), jets written to J ----------------
    {
        const float w0 = W1[j], w1 = W1[64 + j], bb = b1[j];
        #pragma unroll
        for (int r = 0; r < 4; ++r) {
            const int p = q * 4 + r;
            float o[12];
            {   // interior jet at (x,t)
                const float zv = fmaf(px[r], w0, fmaf(pt[r], w1, bb));
                const float a  = ftanh(zv);
                const float d1 = 1.f - a * a;
                const float d2 = -2.f * a * d1;
                o[0] = a; o[1] = d1 * w0; o[2] = d1 * w1;
                o[3] = d2 * w0 * w0; o[4] = d2 * w0 * w1; o[5] = d2 * w1 * w1;
            }
            {   // boundary jet at (1,t)
                const float zv = w0 + fmaf(pt[r], w1, bb);
                const float a  = ftanh(zv);
                const float d1 = 1.f - a * a;
                const float d2 = -2.f * a * d1;
                const float d3 = -2.f * (d1 * d1 + a * d2);
                o[6] = a; o[7] = d1 * w0; o[8] = d1 * w1;
                o[9] = d2 * w0 * w1; o[10] = d2 * w1 * w1; o[11] = d3 * w0 * w1 * w1;
            }
            #pragma unroll
            for (int c = 0; c < 12; ++c)
                Jl[swidx(c * 16 + p, j)] = (half_t)o[c];
        }
    }

    // ---------------- hidden layers 2,3: MFMA jet-GEMM + compose ----------------
    #pragma unroll 1
    for (int layer = 0; layer < 2; ++layer) {
        const half_t* Wt = wsH + layer * 4096;   // [n][k] f16
        const float*  bs = layer ? b3 : b2;

        // B-fragments from global (L1-resident): B[k][n], n = j, k-chunk by q
        const half8 bf0 = *(const half8*)(Wt + j * 64 + q * 8);
        const half8 bf1 = *(const half8*)(Wt + j * 64 + 32 + q * 8);

        __syncthreads();   // J ready

        f32x4 acc[12];
        #pragma unroll
        for (int mt = 0; mt < 12; ++mt) {
            const int m = mt * 16 + i;
            const half8 a0 = *(const half8*)(Jl + swidx(m, q * 8));
            const half8 a1 = *(const half8*)(Jl + swidx(m, 32 + q * 8));
            f32x4 z = {0.f, 0.f, 0.f, 0.f};
            z = __builtin_amdgcn_mfma_f32_16x16x32_f16(a0, bf0, z, 0, 0, 0);
            z = __builtin_amdgcn_mfma_f32_16x16x32_f16(a1, bf1, z, 0, 0, 0);
            acc[mt] = z;
        }

        __syncthreads();   // all reads of J done

        // lane holds Z[c][p=q*4+r][j] in acc[c][r] -> tanh jet composition
        const float bj = bs[j];
        #pragma unroll
        for (int r = 0; r < 4; ++r) {
            const int p = q * 4 + r;
            const float zv = acc[0][r] + bj, zx = acc[1][r], zt = acc[2][r];
            const float zxx = acc[3][r], zxt = acc[4][r], ztt = acc[5][r];
            const float a  = ftanh(zv);
            const float d1 = 1.f - a * a;
            const float d2 = -2.f * a * d1;
            const float zvB = acc[6][r] + bj, zxB = acc[7][r], ztB = acc[8][r];
            const float zxtB = acc[9][r], zttB = acc[10][r], zxttB = acc[11][r];
            const float aB = ftanh(zvB);
            const float e1 = 1.f - aB * aB;
            const float e2 = -2.f * aB * e1;
            const float e3 = -2.f * (e1 * e1 + aB * e2);
            float o[12];
            o[0] = a;
            o[1] = d1 * zx;
            o[2] = d1 * zt;
            o[3] = fmaf(d2 * zx, zx, d1 * zxx);
            o[4] = fmaf(d2 * zx, zt, d1 * zxt);
            o[5] = fmaf(d2 * zt, zt, d1 * ztt);
            o[6] = aB;
            o[7] = e1 * zxB;
            o[8] = e1 * ztB;
            o[9]  = fmaf(e2 * zxB, ztB, e1 * zxtB);
            o[10] = fmaf(e2 * ztB, ztB, e1 * zttB);
            o[11] = e3 * zxB * ztB * ztB + e2 * (2.f * zxtB * ztB + zxB * zttB)
                  + e1 * zxttB;
            #pragma unroll
            for (int c = 0; c < 12; ++c)
                Jl[swidx(c * 16 + p, j)] = (half_t)o[c];
        }
    }

    __syncthreads();   // J3 ready

    // ---------------- output GEMV (Wo in B col 0) + residual ----------------
    if (w == 0) {
        const half_t* WoH = wsH + 8192;
        half8 c0 = {0, 0, 0, 0, 0, 0, 0, 0};
        half8 c1 = {0, 0, 0, 0, 0, 0, 0, 0};
        if (i == 0) {
            c0 = *(const half8*)(WoH + q * 8);
            c1 = *(const half8*)(WoH + 32 + q * 8);
        }

        f32x4 acc[12];
        #pragma unroll
        for (int mt = 0; mt < 12; ++mt) {
            const int m = mt * 16 + i;
            const half8 a0 = *(const half8*)(Jl + swidx(m, q * 8));
            const half8 a1 = *(const half8*)(Jl + swidx(m, 32 + q * 8));
            f32x4 z = {0.f, 0.f, 0.f, 0.f};
            z = __builtin_amdgcn_mfma_f32_16x16x32_f16(a0, c0, z, 0, 0, 0);
            z = __builtin_amdgcn_mfma_f32_16x16x32_f16(a1, c1, z, 0, 0, 0);
            acc[mt] = z;
        }

        if (i == 0) {   // lanes 0,16,32,48 hold u[c] for p = q*4 + r
            float sum4 = 0.f;
            #pragma unroll
            for (int r = 0; r < 4; ++r) {
                const float x = px[r], t = pt[r];
                const float D   = acc[0][r] - acc[6][r] - acc[7][r];
                const float Dx  = acc[1][r];
                const float Dt  = acc[2][r] - acc[8][r] - acc[9][r];
                const float Dxx = acc[3][r];
                const float Dxt = acc[4][r];
                const float Dtt = acc[5][r] - acc[10][r] - acc[11][r];

                // sin(pi t) = v_sin(t/2), cos(pi t) = v_cos(t/2)  [revolutions]
                const float s  = __builtin_amdgcn_sinf(0.5f * t);
                const float cc = __builtin_amdgcn_cosf(0.5f * t);
                const float A  = t * t - t,  Ap = 2.f * t - 1.f;
                const float B  = x * x - x,  Bp = 2.f * x - 1.f;

                const float psi    = 2.f * x * s + A * B * D;
                const float psi_x  = 2.f * s + A * (Bp * D + B * Dx);
                const float psi_xx = A * (2.f * D + 2.f * Bp * Dx + B * Dxx);
                const float psi_xt = 2.f * PI_F * cc + Ap * (Bp * D + B * Dx)
                                   + A * (Bp * Dt + B * Dxt);
                const float psi_tt = -2.f * PI_F * PI_F * x * s + 2.f * B * D
                                   + 2.f * Ap * B * Dt + A * B * Dtt;

                const float forcing = s * (2.f - PI_F * PI_F * x * x
                                           + 2.f * x * x * x * s);
                const float res = psi_xx + 2.f * psi_xt + psi_tt
                                + psi * psi_x - forcing;
                sum4 += fabsf(res);
            }
            rbuf[unit * 4 + q] = sum4;
        }
    }
    __syncthreads();

    if (tid == 0) {
        float s = 0.f;
        #pragma unroll
        for (int k2 = 0; k2 < 8; ++k2) s += rbuf[k2];
        partial[blockIdx.x] = s;
    }
}

__global__ __launch_bounds__(256) void pinn_prep(
    const float* __restrict__ W2, const float* __restrict__ W3,
    const float* __restrict__ Wo, half_t* __restrict__ wsH)
{
    const int tid = threadIdx.x;
    for (int idx = tid; idx < 4096; idx += 256) {
        const int n = idx >> 6, k = idx & 63;
        wsH[idx]        = (half_t)W2[k * 64 + n];   // Wt2[n][k]
        wsH[4096 + idx] = (half_t)W3[k * 64 + n];   // Wt3[n][k]
    }
    if (tid < 64) wsH[8192 + tid] = (half_t)Wo[tid];
}

__global__ __launch_bounds__(256) void pinn_reduce(
    const float* __restrict__ partial, float* __restrict__ out,
    int nblocks, float invN)
{
    __shared__ float sd[256];
    float s = 0.f;
    for (int i = threadIdx.x; i < nblocks; i += 256) s += partial[i];
    sd[threadIdx.x] = s;
    __syncthreads();
    #pragma unroll
    for (int off = 128; off > 0; off >>= 1) {
        if (threadIdx.x < off) sd[threadIdx.x] += sd[threadIdx.x + off];
        __syncthreads();
    }
    if (threadIdx.x == 0) out[0] = sd[0] * invN;
}

extern "C" void kernel_launch(void* const* d_in, const int* in_sizes, int n_in,
                              void* d_out, int out_size, void* d_ws, size_t ws_size,
                              hipStream_t stream)
{
    const float* pts = (const float*)d_in[0];
    const float* W1  = (const float*)d_in[1];
    const float* b1  = (const float*)d_in[2];
    const float* W2  = (const float*)d_in[3];
    const float* b2  = (const float*)d_in[4];
    const float* W3  = (const float*)d_in[5];
    const float* b3  = (const float*)d_in[6];
    const float* Wo  = (const float*)d_in[7];
    // d_in[8] = bo: cancels in (u - u(1,t)) and has zero derivative.

    const int nPts    = in_sizes[0] / 2;          // 262144
    const int nBlocks = nPts / 32;                // 8192 (32 points/block)

    half_t* wsH    = (half_t*)d_ws;                       // 33,024 B of weights
    float*  partial = (float*)((char*)d_ws + 32768);      // 32 KB of partials

    pinn_prep<<<1, 256, 0, stream>>>(W2, W3, Wo, wsH);
    pinn_main<<<nBlocks, 512, 0, stream>>>(pts, W1, b1, b2, b3, wsH, partial);
    pinn_reduce<<<1, 256, 0, stream>>>(partial, (float*)d_out, nBlocks,
                                       1.f / (float)nPts);
}

// Round 5
// 292.031 us; speedup vs baseline: 1.9402x; 1.9402x over previous
//
#include <hip/hip_runtime.h>
#include <math.h>

typedef _Float16 half_t;
typedef half_t half8 __attribute__((ext_vector_type(8)));
typedef float f32x4 __attribute__((ext_vector_type(4)));

#define PI_F 3.14159265358979323846f

// Fast tanh: (e^{2z}-1) * rcp(e^{2z}+1) via native v_exp_f32 / v_rcp_f32.
// Clamp keeps e^{2z} finite (avoids inf*0 = NaN); tanh saturates long before.
// Accuracy validated on-harness in R4 (absmax 0.0 vs fp32 reference path).
__device__ __forceinline__ float ftanh(float z) {
    z = fminf(fmaxf(z, -15.f), 15.f);
    const float t = __expf(2.f * z);          // v_exp_f32
    return (t - 1.f) * __builtin_amdgcn_rcpf(t + 1.f);
}

// J LDS layout: 192 rows (m = comp*16 + point) x 64 half cols (k = neuron).
// Row = 8 granules of 8 halves (16B); granule column rotated by
// s(m) = (m + m>>3) & 7 so the 16 rows of an A-fragment read map to
// distinct-ish bank groups (plain row-major would be a 16-way conflict).
__device__ __forceinline__ int swidx(int m, int col) {
    const int s = (m + (m >> 3)) & 7;
    return m * 64 + ((((col >> 3) + s) & 7) << 3) + (col & 7);
}

// NOTE: no occupancy arg! R4's __launch_bounds__(512,6) forced VGPR 76->40,
// spilling acc[] to scratch: FETCH_SIZE went 1.2MB -> 1GB, dur 300 -> 566us.
__global__ __launch_bounds__(512) void pinn_main(
    const float* __restrict__ pts,
    const float* __restrict__ W1, const float* __restrict__ b1,
    const float* __restrict__ b2, const float* __restrict__ b3,
    const half_t* __restrict__ wsH,    // Wt2 @0, Wt3 @4096, Wo @8192 (half idx)
    float* __restrict__ partial)
{
    __shared__ half_t J[2][192 * 64];   // 2 units x 24 KB
    __shared__ float rbuf[8];

    const int tid  = threadIdx.x;
    const int unit = tid >> 8;          // 16-point unit (4 waves each)
    const int l    = tid & 63;
    const int w    = (tid >> 6) & 3;    // wave within unit = N-tile
    const int q    = l >> 4;
    const int i    = l & 15;
    const int j    = w * 16 + i;        // output-neuron column owned
    half_t* Jl = J[unit];

    const int pbase = blockIdx.x * 32 + unit * 16;

    // points p = q*4 + r live in this lane's registers
    float px[4], pt[4];
    #pragma unroll
    for (int r = 0; r < 4; ++r) {
        const float2 xy = *(const float2*)(pts + 2 * (pbase + q * 4 + r));
        px[r] = xy.x; pt[r] = xy.y;
    }

    // ---------------- layer 1 (2 -> 64), jets written to J ----------------
    {
        const float w0 = W1[j], w1 = W1[64 + j], bb = b1[j];
        #pragma unroll
        for (int r = 0; r < 4; ++r) {
            const int p = q * 4 + r;
            float o[12];
            {   // interior jet at (x,t)
                const float zv = fmaf(px[r], w0, fmaf(pt[r], w1, bb));
                const float a  = ftanh(zv);
                const float d1 = 1.f - a * a;
                const float d2 = -2.f * a * d1;
                o[0] = a; o[1] = d1 * w0; o[2] = d1 * w1;
                o[3] = d2 * w0 * w0; o[4] = d2 * w0 * w1; o[5] = d2 * w1 * w1;
            }
            {   // boundary jet at (1,t)
                const float zv = w0 + fmaf(pt[r], w1, bb);
                const float a  = ftanh(zv);
                const float d1 = 1.f - a * a;
                const float d2 = -2.f * a * d1;
                const float d3 = -2.f * (d1 * d1 + a * d2);
                o[6] = a; o[7] = d1 * w0; o[8] = d1 * w1;
                o[9] = d2 * w0 * w1; o[10] = d2 * w1 * w1; o[11] = d3 * w0 * w1 * w1;
            }
            #pragma unroll
            for (int c = 0; c < 12; ++c)
                Jl[swidx(c * 16 + p, j)] = (half_t)o[c];
        }
    }

    // ---------------- hidden layers 2,3: MFMA jet-GEMM + compose ----------------
    #pragma unroll 1
    for (int layer = 0; layer < 2; ++layer) {
        const half_t* Wt = wsH + layer * 4096;   // [n][k] f16
        const float*  bs = layer ? b3 : b2;

        // B-fragments from global (L1-resident): B[k][n], n = j, k-chunk by q
        const half8 bf0 = *(const half8*)(Wt + j * 64 + q * 8);
        const half8 bf1 = *(const half8*)(Wt + j * 64 + 32 + q * 8);

        __syncthreads();   // J ready

        f32x4 acc[12];
        #pragma unroll
        for (int mt = 0; mt < 12; ++mt) {
            const int m = mt * 16 + i;
            const half8 a0 = *(const half8*)(Jl + swidx(m, q * 8));
            const half8 a1 = *(const half8*)(Jl + swidx(m, 32 + q * 8));
            f32x4 z = {0.f, 0.f, 0.f, 0.f};
            z = __builtin_amdgcn_mfma_f32_16x16x32_f16(a0, bf0, z, 0, 0, 0);
            z = __builtin_amdgcn_mfma_f32_16x16x32_f16(a1, bf1, z, 0, 0, 0);
            acc[mt] = z;
        }

        __syncthreads();   // all reads of J done

        // lane holds Z[c][p=q*4+r][j] in acc[c][r] -> tanh jet composition
        const float bj = bs[j];
        #pragma unroll
        for (int r = 0; r < 4; ++r) {
            const int p = q * 4 + r;
            const float zv = acc[0][r] + bj, zx = acc[1][r], zt = acc[2][r];
            const float zxx = acc[3][r], zxt = acc[4][r], ztt = acc[5][r];
            const float a  = ftanh(zv);
            const float d1 = 1.f - a * a;
            const float d2 = -2.f * a * d1;
            const float zvB = acc[6][r] + bj, zxB = acc[7][r], ztB = acc[8][r];
            const float zxtB = acc[9][r], zttB = acc[10][r], zxttB = acc[11][r];
            const float aB = ftanh(zvB);
            const float e1 = 1.f - aB * aB;
            const float e2 = -2.f * aB * e1;
            const float e3 = -2.f * (e1 * e1 + aB * e2);
            float o[12];
            o[0] = a;
            o[1] = d1 * zx;
            o[2] = d1 * zt;
            o[3] = fmaf(d2 * zx, zx, d1 * zxx);
            o[4] = fmaf(d2 * zx, zt, d1 * zxt);
            o[5] = fmaf(d2 * zt, zt, d1 * ztt);
            o[6] = aB;
            o[7] = e1 * zxB;
            o[8] = e1 * ztB;
            o[9]  = fmaf(e2 * zxB, ztB, e1 * zxtB);
            o[10] = fmaf(e2 * ztB, ztB, e1 * zttB);
            o[11] = e3 * zxB * ztB * ztB + e2 * (2.f * zxtB * ztB + zxB * zttB)
                  + e1 * zxttB;
            #pragma unroll
            for (int c = 0; c < 12; ++c)
                Jl[swidx(c * 16 + p, j)] = (half_t)o[c];
        }
    }

    __syncthreads();   // J3 ready

    // ---------------- output GEMV (Wo in B col 0) + residual ----------------
    if (w == 0) {
        const half_t* WoH = wsH + 8192;
        half8 c0 = {0, 0, 0, 0, 0, 0, 0, 0};
        half8 c1 = {0, 0, 0, 0, 0, 0, 0, 0};
        if (i == 0) {
            c0 = *(const half8*)(WoH + q * 8);
            c1 = *(const half8*)(WoH + 32 + q * 8);
        }

        f32x4 acc[12];
        #pragma unroll
        for (int mt = 0; mt < 12; ++mt) {
            const int m = mt * 16 + i;
            const half8 a0 = *(const half8*)(Jl + swidx(m, q * 8));
            const half8 a1 = *(const half8*)(Jl + swidx(m, 32 + q * 8));
            f32x4 z = {0.f, 0.f, 0.f, 0.f};
            z = __builtin_amdgcn_mfma_f32_16x16x32_f16(a0, c0, z, 0, 0, 0);
            z = __builtin_amdgcn_mfma_f32_16x16x32_f16(a1, c1, z, 0, 0, 0);
            acc[mt] = z;
        }

        if (i == 0) {   // lanes 0,16,32,48 hold u[c] for p = q*4 + r
            float sum4 = 0.f;
            #pragma unroll
            for (int r = 0; r < 4; ++r) {
                const float x = px[r], t = pt[r];
                const float D   = acc[0][r] - acc[6][r] - acc[7][r];
                const float Dx  = acc[1][r];
                const float Dt  = acc[2][r] - acc[8][r] - acc[9][r];
                const float Dxx = acc[3][r];
                const float Dxt = acc[4][r];
                const float Dtt = acc[5][r] - acc[10][r] - acc[11][r];

                // sin(pi t) = v_sin(t/2), cos(pi t) = v_cos(t/2)  [revolutions]
                const float s  = __builtin_amdgcn_sinf(0.5f * t);
                const float cc = __builtin_amdgcn_cosf(0.5f * t);
                const float A  = t * t - t,  Ap = 2.f * t - 1.f;
                const float B  = x * x - x,  Bp = 2.f * x - 1.f;

                const float psi    = 2.f * x * s + A * B * D;
                const float psi_x  = 2.f * s + A * (Bp * D + B * Dx);
                const float psi_xx = A * (2.f * D + 2.f * Bp * Dx + B * Dxx);
                const float psi_xt = 2.f * PI_F * cc + Ap * (Bp * D + B * Dx)
                                   + A * (Bp * Dt + B * Dxt);
                const float psi_tt = -2.f * PI_F * PI_F * x * s + 2.f * B * D
                                   + 2.f * Ap * B * Dt + A * B * Dtt;

                const float forcing = s * (2.f - PI_F * PI_F * x * x
                                           + 2.f * x * x * x * s);
                const float res = psi_xx + 2.f * psi_xt + psi_tt
                                + psi * psi_x - forcing;
                sum4 += fabsf(res);
            }
            rbuf[unit * 4 + q] = sum4;
        }
    }
    __syncthreads();

    if (tid == 0) {
        float s = 0.f;
        #pragma unroll
        for (int k2 = 0; k2 < 8; ++k2) s += rbuf[k2];
        partial[blockIdx.x] = s;
    }
}

__global__ __launch_bounds__(256) void pinn_prep(
    const float* __restrict__ W2, const float* __restrict__ W3,
    const float* __restrict__ Wo, half_t* __restrict__ wsH)
{
    const int tid = threadIdx.x;
    for (int idx = tid; idx < 4096; idx += 256) {
        const int n = idx >> 6, k = idx & 63;
        wsH[idx]        = (half_t)W2[k * 64 + n];   // Wt2[n][k]
        wsH[4096 + idx] = (half_t)W3[k * 64 + n];   // Wt3[n][k]
    }
    if (tid < 64) wsH[8192 + tid] = (half_t)Wo[tid];
}

__global__ __launch_bounds__(256) void pinn_reduce(
    const float* __restrict__ partial, float* __restrict__ out,
    int nblocks, float invN)
{
    __shared__ float sd[256];
    float s = 0.f;
    for (int i = threadIdx.x; i < nblocks; i += 256) s += partial[i];
    sd[threadIdx.x] = s;
    __syncthreads();
    #pragma unroll
    for (int off = 128; off > 0; off >>= 1) {
        if (threadIdx.x < off) sd[threadIdx.x] += sd[threadIdx.x + off];
        __syncthreads();
    }
    if (threadIdx.x == 0) out[0] = sd[0] * invN;
}

extern "C" void kernel_launch(void* const* d_in, const int* in_sizes, int n_in,
                              void* d_out, int out_size, void* d_ws, size_t ws_size,
                              hipStream_t stream)
{
    const float* pts = (const float*)d_in[0];
    const float* W1  = (const float*)d_in[1];
    const float* b1  = (const float*)d_in[2];
    const float* W2  = (const float*)d_in[3];
    const float* b2  = (const float*)d_in[4];
    const float* W3  = (const float*)d_in[5];
    const float* b3  = (const float*)d_in[6];
    const float* Wo  = (const float*)d_in[7];
    // d_in[8] = bo: cancels in (u - u(1,t)) and has zero derivative.

    const int nPts    = in_sizes[0] / 2;          // 262144
    const int nBlocks = nPts / 32;                // 8192 (32 points/block)

    half_t* wsH    = (half_t*)d_ws;                       // 33,024 B of weights
    float*  partial = (float*)((char*)d_ws + 32768);      // 32 KB of partials

    pinn_prep<<<1, 256, 0, stream>>>(W2, W3, Wo, wsH);
    pinn_main<<<nBlocks, 512, 0, stream>>>(pts, W1, b1, b2, b3, wsH, partial);
    pinn_reduce<<<1, 256, 0, stream>>>(partial, (float*)d_out, nBlocks,
                                       1.f / (float)nPts);
}

// Round 6
// 169.906 us; speedup vs baseline: 3.3348x; 1.7188x over previous
//
#include <hip/hip_runtime.h>
#include <math.h>

typedef _Float16 half_t;
typedef half_t half8 __attribute__((ext_vector_type(8)));
typedef float f32x4 __attribute__((ext_vector_type(4)));

#define PI_F 3.14159265358979323846f

// Fast tanh: (e^{2z}-1) * rcp(e^{2z}+1). Validated on-harness (absmax 0.0).
__device__ __forceinline__ float ftanh(float z) {
    z = fminf(fmaxf(z, -15.f), 15.f);
    const float t = __expf(2.f * z);          // v_exp_f32
    return (t - 1.f) * __builtin_amdgcn_rcpf(t + 1.f);
}

// XOR-swizzled J[192][64] (halves): idx(m,col) = m*64 + (((col>>3)^(m&7))<<3) + (col&7).
// Reads (m = mt*16+i):  m&7 = i&7  -> column part lane-constant, mt stride = 1024 halves.
// Writes (m = c*16+p):  m&7 = p&7  -> column part r-constant,    c  stride = 1024 halves.
// So all ds ops become base + compile-time offset (offset: immediate), no per-access VALU.
// Conflicts: within a 16-lane quarter, granule = q^(i&7) -> 8 granules x 2 lanes = free.

// NOTE: no occupancy arg in launch_bounds (R4: (512,6) caused acc[] spill, 2.2GB scratch).
__global__ __launch_bounds__(256) void pinn_main(
    const float* __restrict__ pts,
    const float* __restrict__ W1, const float* __restrict__ b1,
    const float* __restrict__ b2, const float* __restrict__ b3,
    const half_t* __restrict__ wsH,    // Wt2 @0, Wt3 @4096, Wo @8192 (half idx)
    float* __restrict__ partial)
{
    __shared__ __align__(16) half_t J[192 * 64];   // 24 KB, single 16-point unit

    const int tid = threadIdx.x;
    const int l   = tid & 63;
    const int w   = tid >> 6;       // wave 0..3 = output-neuron N-tile
    const int q   = l >> 4;
    const int i   = l & 15;
    const int j   = w * 16 + i;     // neuron column owned

    // loop-invariant LDS bases (halves)
    const int rb0 = i * 64 + ((q ^ (i & 7)) << 3);         // A-frag, k-chunk q*8
    const int rb1 = i * 64 + (((4 + q) ^ (i & 7)) << 3);   // A-frag, k-chunk 32+q*8

    // pass-invariant weights/biases hoisted to registers
    const half8 w2a = *(const half8*)(wsH + j * 64 + q * 8);
    const half8 w2b = *(const half8*)(wsH + j * 64 + 32 + q * 8);
    const half8 w3a = *(const half8*)(wsH + 4096 + j * 64 + q * 8);
    const half8 w3b = *(const half8*)(wsH + 4096 + j * 64 + 32 + q * 8);
    const float bj2 = b2[j], bj3 = b3[j];
    const float w0 = W1[j], w1 = W1[64 + j], bb = b1[j];

    half8 wo0 = {0, 0, 0, 0, 0, 0, 0, 0};
    half8 wo1 = {0, 0, 0, 0, 0, 0, 0, 0};
    if (i == 0) {   // B col 0 = Wo (GEMV); other cols zero
        wo0 = *(const half8*)(wsH + 8192 + q * 8);
        wo1 = *(const half8*)(wsH + 8192 + 32 + q * 8);
    }

    float bsum = 0.f;

    #pragma unroll 1
    for (int pass = 0; pass < 2; ++pass) {
        const int pbase = blockIdx.x * 32 + pass * 16;

        float px[4], pt4[4];
        #pragma unroll
        for (int r = 0; r < 4; ++r) {
            const float2 xy = *(const float2*)(pts + 2 * (pbase + q * 4 + r));
            px[r] = xy.x; pt4[r] = xy.y;
        }

        // ---------------- layer 1 (2 -> 64) ----------------
        #pragma unroll
        for (int r = 0; r < 4; ++r) {
            const int p  = q * 4 + r;
            const int wb = p * 64 + ((((j >> 3) ^ p) & 7) << 3) + (j & 7);
            {   // interior jet at (x,t)
                const float zv = fmaf(px[r], w0, fmaf(pt4[r], w1, bb));
                const float a  = ftanh(zv);
                const float d1 = 1.f - a * a;
                const float d2 = -2.f * a * d1;
                J[wb]            = (half_t)a;
                J[wb + 1 * 1024] = (half_t)(d1 * w0);
                J[wb + 2 * 1024] = (half_t)(d1 * w1);
                J[wb + 3 * 1024] = (half_t)(d2 * w0 * w0);
                J[wb + 4 * 1024] = (half_t)(d2 * w0 * w1);
                J[wb + 5 * 1024] = (half_t)(d2 * w1 * w1);
            }
            {   // boundary jet at (1,t)
                const float zv = w0 + fmaf(pt4[r], w1, bb);
                const float a  = ftanh(zv);
                const float d1 = 1.f - a * a;
                const float d2 = -2.f * a * d1;
                const float d3 = -2.f * (d1 * d1 + a * d2);
                J[wb + 6 * 1024]  = (half_t)a;
                J[wb + 7 * 1024]  = (half_t)(d1 * w0);
                J[wb + 8 * 1024]  = (half_t)(d1 * w1);
                J[wb + 9 * 1024]  = (half_t)(d2 * w0 * w1);
                J[wb + 10 * 1024] = (half_t)(d2 * w1 * w1);
                J[wb + 11 * 1024] = (half_t)(d3 * w0 * w1 * w1);
            }
        }

        // ---------------- hidden layer: MFMA jet-GEMM + compose ----------------
        auto layer_step = [&](const half8 wa, const half8 wb8, const float bj) {
            __syncthreads();   // J ready
            f32x4 acc[12];
            #pragma unroll
            for (int mt = 0; mt < 12; ++mt) {
                const half8 a0 = *(const half8*)(J + rb0 + mt * 1024);
                const half8 a1 = *(const half8*)(J + rb1 + mt * 1024);
                f32x4 z = {0.f, 0.f, 0.f, 0.f};
                z = __builtin_amdgcn_mfma_f32_16x16x32_f16(a0, wa,  z, 0, 0, 0);
                z = __builtin_amdgcn_mfma_f32_16x16x32_f16(a1, wb8, z, 0, 0, 0);
                acc[mt] = z;
            }
            __syncthreads();   // all reads of J done

            #pragma unroll
            for (int r = 0; r < 4; ++r) {
                const int p  = q * 4 + r;
                const int wb = p * 64 + ((((j >> 3) ^ p) & 7) << 3) + (j & 7);
                const float zv = acc[0][r] + bj, zx = acc[1][r], zt = acc[2][r];
                const float zxx = acc[3][r], zxt = acc[4][r], ztt = acc[5][r];
                const float a  = ftanh(zv);
                const float d1 = 1.f - a * a;
                const float d2 = -2.f * a * d1;
                const float zvB = acc[6][r] + bj, zxB = acc[7][r], ztB = acc[8][r];
                const float zxtB = acc[9][r], zttB = acc[10][r], zxttB = acc[11][r];
                const float aB = ftanh(zvB);
                const float e1 = 1.f - aB * aB;
                const float e2 = -2.f * aB * e1;
                const float e3 = -2.f * (e1 * e1 + aB * e2);
                J[wb]            = (half_t)a;
                J[wb + 1 * 1024] = (half_t)(d1 * zx);
                J[wb + 2 * 1024] = (half_t)(d1 * zt);
                J[wb + 3 * 1024] = (half_t)fmaf(d2 * zx, zx, d1 * zxx);
                J[wb + 4 * 1024] = (half_t)fmaf(d2 * zx, zt, d1 * zxt);
                J[wb + 5 * 1024] = (half_t)fmaf(d2 * zt, zt, d1 * ztt);
                J[wb + 6 * 1024]  = (half_t)aB;
                J[wb + 7 * 1024]  = (half_t)(e1 * zxB);
                J[wb + 8 * 1024]  = (half_t)(e1 * ztB);
                J[wb + 9 * 1024]  = (half_t)fmaf(e2 * zxB, ztB, e1 * zxtB);
                J[wb + 10 * 1024] = (half_t)fmaf(e2 * ztB, ztB, e1 * zttB);
                J[wb + 11 * 1024] = (half_t)(e3 * zxB * ztB * ztB
                                   + e2 * (2.f * zxtB * ztB + zxB * zttB)
                                   + e1 * zxttB);
            }
        };
        layer_step(w2a, w2b, bj2);
        layer_step(w3a, w3b, bj3);
        __syncthreads();   // J3 ready

        // ---------------- output GEMV (Wo in B col 0) + residual ----------------
        float s4 = 0.f;
        if (w == 0) {
            f32x4 u[12];
            #pragma unroll
            for (int mt = 0; mt < 12; ++mt) {
                const half8 a0 = *(const half8*)(J + rb0 + mt * 1024);
                const half8 a1 = *(const half8*)(J + rb1 + mt * 1024);
                f32x4 z = {0.f, 0.f, 0.f, 0.f};
                z = __builtin_amdgcn_mfma_f32_16x16x32_f16(a0, wo0, z, 0, 0, 0);
                z = __builtin_amdgcn_mfma_f32_16x16x32_f16(a1, wo1, z, 0, 0, 0);
                u[mt] = z;
            }
            if (i == 0) {   // lanes 0,16,32,48: u[c][r] for p = q*4 + r
                #pragma unroll
                for (int r = 0; r < 4; ++r) {
                    const float x = px[r], t = pt4[r];
                    const float D   = u[0][r] - u[6][r] - u[7][r];
                    const float Dx  = u[1][r];
                    const float Dt  = u[2][r] - u[8][r] - u[9][r];
                    const float Dxx = u[3][r];
                    const float Dxt = u[4][r];
                    const float Dtt = u[5][r] - u[10][r] - u[11][r];

                    // sin(pi t) = v_sin(t/2) [revolutions], t in [0,1]
                    const float s  = __builtin_amdgcn_sinf(0.5f * t);
                    const float cc = __builtin_amdgcn_cosf(0.5f * t);
                    const float A  = t * t - t,  Ap = 2.f * t - 1.f;
                    const float B  = x * x - x,  Bp = 2.f * x - 1.f;

                    const float psi    = 2.f * x * s + A * B * D;
                    const float psi_x  = 2.f * s + A * (Bp * D + B * Dx);
                    const float psi_xx = A * (2.f * D + 2.f * Bp * Dx + B * Dxx);
                    const float psi_xt = 2.f * PI_F * cc + Ap * (Bp * D + B * Dx)
                                       + A * (Bp * Dt + B * Dxt);
                    const float psi_tt = -2.f * PI_F * PI_F * x * s + 2.f * B * D
                                       + 2.f * Ap * B * Dt + A * B * Dtt;

                    const float forcing = s * (2.f - PI_F * PI_F * x * x
                                               + 2.f * x * x * x * s);
                    const float res = psi_xx + 2.f * psi_xt + psi_tt
                                    + psi * psi_x - forcing;
                    s4 += fabsf(res);
                }
            }
            s4 += __shfl_xor(s4, 16, 64);
            s4 += __shfl_xor(s4, 32, 64);
            if (l == 0) bsum += s4;
        }
        __syncthreads();   // J free for next pass
    }

    if (tid == 0) partial[blockIdx.x] = bsum;
}

__global__ __launch_bounds__(256) void pinn_prep(
    const float* __restrict__ W2, const float* __restrict__ W3,
    const float* __restrict__ Wo, half_t* __restrict__ wsH)
{
    const int tid = threadIdx.x;
    for (int idx = tid; idx < 4096; idx += 256) {
        const int n = idx >> 6, k = idx & 63;
        wsH[idx]        = (half_t)W2[k * 64 + n];   // Wt2[n][k]
        wsH[4096 + idx] = (half_t)W3[k * 64 + n];   // Wt3[n][k]
    }
    if (tid < 64) wsH[8192 + tid] = (half_t)Wo[tid];
}

__global__ __launch_bounds__(256) void pinn_reduce(
    const float* __restrict__ partial, float* __restrict__ out,
    int nblocks, float invN)
{
    __shared__ float sd[256];
    float s = 0.f;
    for (int i = threadIdx.x; i < nblocks; i += 256) s += partial[i];
    sd[threadIdx.x] = s;
    __syncthreads();
    #pragma unroll
    for (int off = 128; off > 0; off >>= 1) {
        if (threadIdx.x < off) sd[threadIdx.x] += sd[threadIdx.x + off];
        __syncthreads();
    }
    if (threadIdx.x == 0) out[0] = sd[0] * invN;
}

extern "C" void kernel_launch(void* const* d_in, const int* in_sizes, int n_in,
                              void* d_out, int out_size, void* d_ws, size_t ws_size,
                              hipStream_t stream)
{
    const float* pts = (const float*)d_in[0];
    const float* W1  = (const float*)d_in[1];
    const float* b1  = (const float*)d_in[2];
    const float* W2  = (const float*)d_in[3];
    const float* b2  = (const float*)d_in[4];
    const float* W3  = (const float*)d_in[5];
    const float* b3  = (const float*)d_in[6];
    const float* Wo  = (const float*)d_in[7];
    // d_in[8] = bo: cancels in (u - u(1,t)) and has zero derivative.

    const int nPts    = in_sizes[0] / 2;          // 262144
    const int nBlocks = nPts / 32;                // 8192 (32 pts = 2 passes x 16)

    half_t* wsH     = (half_t*)d_ws;                      // 16,512 B of weights
    float*  partial = (float*)((char*)d_ws + 32768);      // 32 KB of partials

    pinn_prep<<<1, 256, 0, stream>>>(W2, W3, Wo, wsH);
    pinn_main<<<nBlocks, 256, 0, stream>>>(pts, W1, b1, b2, b3, wsH, partial);
    pinn_reduce<<<1, 256, 0, stream>>>(partial, (float*)d_out, nBlocks,
                                       1.f / (float)nPts);
}

// Round 8
// 148.848 us; speedup vs baseline: 3.8065x; 1.1415x over previous
//
#include <hip/hip_runtime.h>
#include <math.h>

typedef _Float16 half_t;
typedef half_t half8 __attribute__((ext_vector_type(8)));
typedef __fp16 fp16x2 __attribute__((ext_vector_type(2)));   // cvt_pkrtz return type
typedef float f32x4 __attribute__((ext_vector_type(4)));

#define PI_F 3.14159265358979323846f

// Fast tanh: (e^{2z}-1) * rcp(e^{2z}+1). Validated on-harness (absmax 0.0).
__device__ __forceinline__ float ftanh(float z) {
    z = fminf(fmaxf(z, -15.f), 15.f);
    const float t = __expf(2.f * z);          // v_exp_f32
    return (t - 1.f) * __builtin_amdgcn_rcpf(t + 1.f);
}

// XOR-swizzled J[192][64] (halves): idx(m,col) = m*64 + (((col>>3)^(m&7))<<3) + (col&7).
// Reads (m = mt*16+i):  m&7 = i&7  -> base lane-constant, mt stride = 1024 halves.
// Writes (m = c*16+p):  m&7 = p&7  -> base r-constant,    c  stride = 1024 halves.
// All ds ops = base + compile-time offset; conflict-free (R6: SQ_LDS_BANK_CONFLICT = 0).

// NOTE: no occupancy arg in launch_bounds (R4: (512,6) caused acc[] spill, 2.2GB scratch).
__global__ __launch_bounds__(256) void pinn_main(
    const float* __restrict__ pts,
    const float* __restrict__ W1, const float* __restrict__ b1,
    const float* __restrict__ b2, const float* __restrict__ b3,
    const half_t* __restrict__ wsH,    // Wt2 @0, Wt3 @4096, Wo @8192 (half idx)
    float* __restrict__ partial)
{
    __shared__ __align__(16) half_t J[192 * 64];   // 24 KB
    __shared__ float ubuf[12][16];                 // u[c][p] stage for residual

    const int tid = threadIdx.x;
    const int l   = tid & 63;
    const int w   = tid >> 6;       // wave 0..3 = output-neuron N-tile
    const int q   = l >> 4;
    const int i   = l & 15;
    const int j   = w * 16 + i;     // neuron column owned

    // loop-invariant LDS bases (halves)
    const int rb0 = i * 64 + ((q ^ (i & 7)) << 3);         // A-frag, k-chunk q*8
    const int rb1 = i * 64 + (((4 + q) ^ (i & 7)) << 3);   // A-frag, k-chunk 32+q*8

    // pass-invariant weights/biases hoisted to registers
    const half8 w2a = *(const half8*)(wsH + j * 64 + q * 8);
    const half8 w2b = *(const half8*)(wsH + j * 64 + 32 + q * 8);
    const half8 w3a = *(const half8*)(wsH + 4096 + j * 64 + q * 8);
    const half8 w3b = *(const half8*)(wsH + 4096 + j * 64 + 32 + q * 8);
    const float bj2 = b2[j], bj3 = b3[j];
    const float w0 = W1[j], w1 = W1[64 + j], bb = b1[j];

    half8 wo0 = {0, 0, 0, 0, 0, 0, 0, 0};   // GEMV B col 0 = Wo (all waves now)
    half8 wo1 = {0, 0, 0, 0, 0, 0, 0, 0};
    if (i == 0) {
        wo0 = *(const half8*)(wsH + 8192 + q * 8);
        wo1 = *(const half8*)(wsH + 8192 + 32 + q * 8);
    }

    float bsum = 0.f;

    #pragma unroll 1
    for (int pass = 0; pass < 2; ++pass) {
        const int pbase = blockIdx.x * 32 + pass * 16;

        float px[4], pt4[4];
        #pragma unroll
        for (int r = 0; r < 4; ++r) {
            const float2 xy = *(const float2*)(pts + 2 * (pbase + q * 4 + r));
            px[r] = xy.x; pt4[r] = xy.y;
        }

        // ---------------- layer 1 (2 -> 64) ----------------
        #pragma unroll
        for (int r = 0; r < 4; ++r) {
            const int p  = q * 4 + r;
            const int wb = p * 64 + ((((j >> 3) ^ p) & 7) << 3) + (j & 7);
            float o[12];
            {   // interior jet at (x,t)
                const float zv = fmaf(px[r], w0, fmaf(pt4[r], w1, bb));
                const float a  = ftanh(zv);
                const float d1 = 1.f - a * a;
                const float d2 = -2.f * a * d1;
                o[0] = a; o[1] = d1 * w0; o[2] = d1 * w1;
                o[3] = d2 * w0 * w0; o[4] = d2 * w0 * w1; o[5] = d2 * w1 * w1;
            }
            {   // boundary jet at (1,t)
                const float zv = w0 + fmaf(pt4[r], w1, bb);
                const float a  = ftanh(zv);
                const float d1 = 1.f - a * a;
                const float d2 = -2.f * a * d1;
                const float d3 = -2.f * (d1 * d1 + a * d2);
                o[6] = a; o[7] = d1 * w0; o[8] = d1 * w1;
                o[9] = d2 * w0 * w1; o[10] = d2 * w1 * w1; o[11] = d3 * w0 * w1 * w1;
            }
            #pragma unroll
            for (int cc = 0; cc < 6; ++cc) {   // packed convert, paired stores
                const fp16x2 hv = __builtin_amdgcn_cvt_pkrtz(o[2 * cc], o[2 * cc + 1]);
                J[wb + (2 * cc)     * 1024] = (half_t)hv[0];
                J[wb + (2 * cc + 1) * 1024] = (half_t)hv[1];   // d16_hi store
            }
        }

        // ---------------- hidden layer: MFMA jet-GEMM + compose ----------------
        auto layer_step = [&](const half8 wa, const half8 wb8, const float bj) {
            __syncthreads();   // J ready
            const f32x4 zb = {bj, bj, bj, bj};
            const f32x4 z0 = {0.f, 0.f, 0.f, 0.f};
            f32x4 acc[12];
            #pragma unroll
            for (int mt = 0; mt < 12; ++mt) {
                const half8 a0 = *(const half8*)(J + rb0 + mt * 1024);
                const half8 a1 = *(const half8*)(J + rb1 + mt * 1024);
                f32x4 z = (mt == 0 || mt == 6) ? zb : z0;   // bias folded into C-init
                z = __builtin_amdgcn_mfma_f32_16x16x32_f16(a0, wa,  z, 0, 0, 0);
                z = __builtin_amdgcn_mfma_f32_16x16x32_f16(a1, wb8, z, 0, 0, 0);
                acc[mt] = z;
            }
            __syncthreads();   // all reads of J done

            #pragma unroll
            for (int r = 0; r < 4; ++r) {
                const int p  = q * 4 + r;
                const int wb = p * 64 + ((((j >> 3) ^ p) & 7) << 3) + (j & 7);
                const float zv = acc[0][r], zx = acc[1][r], zt = acc[2][r];
                const float zxx = acc[3][r], zxt = acc[4][r], ztt = acc[5][r];
                const float a  = ftanh(zv);
                const float d1 = 1.f - a * a;
                const float d2 = -2.f * a * d1;
                const float zvB = acc[6][r], zxB = acc[7][r], ztB = acc[8][r];
                const float zxtB = acc[9][r], zttB = acc[10][r], zxttB = acc[11][r];
                const float aB = ftanh(zvB);
                const float e1 = 1.f - aB * aB;
                const float e2 = -2.f * aB * e1;
                const float e3 = -2.f * (e1 * e1 + aB * e2);
                float o[12];
                o[0] = a;
                o[1] = d1 * zx;
                o[2] = d1 * zt;
                o[3] = fmaf(d2 * zx, zx, d1 * zxx);
                o[4] = fmaf(d2 * zx, zt, d1 * zxt);
                o[5] = fmaf(d2 * zt, zt, d1 * ztt);
                o[6] = aB;
                o[7] = e1 * zxB;
                o[8] = e1 * ztB;
                o[9]  = fmaf(e2 * zxB, ztB, e1 * zxtB);
                o[10] = fmaf(e2 * ztB, ztB, e1 * zttB);
                o[11] = e3 * zxB * ztB * ztB + e2 * (2.f * zxtB * ztB + zxB * zttB)
                      + e1 * zxttB;
                #pragma unroll
                for (int cc = 0; cc < 6; ++cc) {
                    const fp16x2 hv = __builtin_amdgcn_cvt_pkrtz(o[2 * cc], o[2 * cc + 1]);
                    J[wb + (2 * cc)     * 1024] = (half_t)hv[0];
                    J[wb + (2 * cc + 1) * 1024] = (half_t)hv[1];
                }
            }
        };
        layer_step(w2a, w2b, bj2);
        layer_step(w3a, w3b, bj3);
        __syncthreads();   // J3 ready

        // -------- output GEMV (Wo in B col 0), split: wave w owns mt = 3w..3w+2 --------
        {
            f32x4 u3[3];
            #pragma unroll
            for (int k3 = 0; k3 < 3; ++k3) {
                const int mt = w * 3 + k3;
                const half8 a0 = *(const half8*)(J + rb0 + mt * 1024);
                const half8 a1 = *(const half8*)(J + rb1 + mt * 1024);
                f32x4 z = {0.f, 0.f, 0.f, 0.f};
                z = __builtin_amdgcn_mfma_f32_16x16x32_f16(a0, wo0, z, 0, 0, 0);
                z = __builtin_amdgcn_mfma_f32_16x16x32_f16(a1, wo1, z, 0, 0, 0);
                u3[k3] = z;
            }
            if (i == 0) {   // col 0 lanes hold u[mt][p = q*4+r]
                #pragma unroll
                for (int k3 = 0; k3 < 3; ++k3)
                    #pragma unroll
                    for (int r = 0; r < 4; ++r)
                        ubuf[w * 3 + k3][q * 4 + r] = u3[k3][r];
            }
        }
        __syncthreads();   // ubuf ready; all J reads done (next-pass layer1 may write J)

        // ---------------- residual: one lane per point ----------------
        if (tid < 16) {
            const float x = pts[2 * (pbase + tid)];
            const float t = pts[2 * (pbase + tid) + 1];
            float U[12];
            #pragma unroll
            for (int c = 0; c < 12; ++c) U[c] = ubuf[c][tid];

            const float D   = U[0] - U[6] - U[7];
            const float Dx  = U[1];
            const float Dt  = U[2] - U[8] - U[9];
            const float Dxx = U[3];
            const float Dxt = U[4];
            const float Dtt = U[5] - U[10] - U[11];

            // sin(pi t) = v_sin(t/2) [revolutions], t in [0,1]
            const float s  = __builtin_amdgcn_sinf(0.5f * t);
            const float cc = __builtin_amdgcn_cosf(0.5f * t);
            const float A  = t * t - t,  Ap = 2.f * t - 1.f;
            const float B  = x * x - x,  Bp = 2.f * x - 1.f;

            const float psi    = 2.f * x * s + A * B * D;
            const float psi_x  = 2.f * s + A * (Bp * D + B * Dx);
            const float psi_xx = A * (2.f * D + 2.f * Bp * Dx + B * Dxx);
            const float psi_xt = 2.f * PI_F * cc + Ap * (Bp * D + B * Dx)
                               + A * (Bp * Dt + B * Dxt);
            const float psi_tt = -2.f * PI_F * PI_F * x * s + 2.f * B * D
                               + 2.f * Ap * B * Dt + A * B * Dtt;

            const float forcing = s * (2.f - PI_F * PI_F * x * x
                                       + 2.f * x * x * x * s);
            float s4 = fabsf(psi_xx + 2.f * psi_xt + psi_tt + psi * psi_x - forcing);
            s4 += __shfl_xor(s4, 1, 64);
            s4 += __shfl_xor(s4, 2, 64);
            s4 += __shfl_xor(s4, 4, 64);
            s4 += __shfl_xor(s4, 8, 64);
            if (tid == 0) bsum += s4;
        }
        // no extra barrier: next-pass J writes are guarded by layer_step's top sync,
        // and ubuf is not rewritten until after 5 more barriers.
    }

    if (tid == 0) partial[blockIdx.x] = bsum;
}

__global__ __launch_bounds__(256) void pinn_prep(
    const float* __restrict__ W2, const float* __restrict__ W3,
    const float* __restrict__ Wo, half_t* __restrict__ wsH)
{
    const int tid = threadIdx.x;
    for (int idx = tid; idx < 4096; idx += 256) {
        const int n = idx >> 6, k = idx & 63;
        wsH[idx]        = (half_t)W2[k * 64 + n];   // Wt2[n][k]
        wsH[4096 + idx] = (half_t)W3[k * 64 + n];   // Wt3[n][k]
    }
    if (tid < 64) wsH[8192 + tid] = (half_t)Wo[tid];
}

__global__ __launch_bounds__(256) void pinn_reduce(
    const float* __restrict__ partial, float* __restrict__ out,
    int nblocks, float invN)
{
    __shared__ float sd[256];
    float s = 0.f;
    for (int i = threadIdx.x; i < nblocks; i += 256) s += partial[i];
    sd[threadIdx.x] = s;
    __syncthreads();
    #pragma unroll
    for (int off = 128; off > 0; off >>= 1) {
        if (threadIdx.x < off) sd[threadIdx.x] += sd[threadIdx.x + off];
        __syncthreads();
    }
    if (threadIdx.x == 0) out[0] = sd[0] * invN;
}

extern "C" void kernel_launch(void* const* d_in, const int* in_sizes, int n_in,
                              void* d_out, int out_size, void* d_ws, size_t ws_size,
                              hipStream_t stream)
{
    const float* pts = (const float*)d_in[0];
    const float* W1  = (const float*)d_in[1];
    const float* b1  = (const float*)d_in[2];
    const float* W2  = (const float*)d_in[3];
    const float* b2  = (const float*)d_in[4];
    const float* W3  = (const float*)d_in[5];
    const float* b3  = (const float*)d_in[6];
    const float* Wo  = (const float*)d_in[7];
    // d_in[8] = bo: cancels in (u - u(1,t)) and has zero derivative.

    const int nPts    = in_sizes[0] / 2;          // 262144
    const int nBlocks = nPts / 32;                // 8192 (32 pts = 2 passes x 16)

    half_t* wsH     = (half_t*)d_ws;                      // 16,512 B of weights
    float*  partial = (float*)((char*)d_ws + 32768);      // 32 KB of partials

    pinn_prep<<<1, 256, 0, stream>>>(W2, W3, Wo, wsH);
    pinn_main<<<nBlocks, 256, 0, stream>>>(pts, W1, b1, b2, b3, wsH, partial);
    pinn_reduce<<<1, 256, 0, stream>>>(partial, (float*)d_out, nBlocks,
                                       1.f / (float)nPts);
}